// Round 1
// baseline (153.717 us; speedup 1.0000x reference)
//
#include <hip/hip_runtime.h>

#define NB 64
#define NF 256
#define TIN 4096
#define TOUT 4096
#define BN_EPS 1e-5f

// -------- helpers --------
__device__ __forceinline__ void waveReduce2(float& s, float& q) {
    #pragma unroll
    for (int off = 32; off > 0; off >>= 1) {
        s += __shfl_down(s, off, 64);
        q += __shfl_down(q, off, 64);
    }
}

__device__ __forceinline__ float resample_one(const float* __restrict__ row,
                                              int t, float s, float st) {
    // exact reference op order, fp32
    float x = (2.0f * (float)t + 1.0f) * (1.0f / (float)TOUT) - 1.0f;
    float coord = s * x + st;
    float ix = ((coord + 1.0f) * (float)TIN - 1.0f) * 0.5f;
    float i0f = floorf(ix);
    float w = ix - i0f;
    int i0 = (int)i0f;
    int i1 = i0 + 1;
    float v0 = (i0 >= 0 && i0 < TIN) ? row[i0] : 0.0f;
    float v1 = (i1 >= 0 && i1 < TIN) ? row[i1] : 0.0f;
    return v0 * (1.0f - w) + v1 * w;
}

// -------- kernel 1: per-(b,f) row resample + partial sum/sumsq --------
__global__ __launch_bounds__(256) void k_resample_stats(
    const float* __restrict__ data,
    const float* __restrict__ translate,
    const float* __restrict__ scale,
    float2* __restrict__ partials)
{
    const int blk = blockIdx.x;
    const int f = blk & (NF - 1);
    const int b = blk >> 8;           // NF == 256
    const float* row_g = data + ((size_t)b * NF + f) * (size_t)TIN;

    __shared__ float row[TIN];
    __shared__ float2 wred[4];

    // stage row into LDS, coalesced float4
    {
        const float4* src4 = (const float4*)row_g;
        float4* dst4 = (float4*)row;
        #pragma unroll
        for (int i = 0; i < TIN / 4 / 256; ++i)
            dst4[threadIdx.x + i * 256] = src4[threadIdx.x + i * 256];
    }
    __syncthreads();

    const float s = expf(scale[f] / 5.0f);
    const float st = s * translate[f];

    float sum = 0.0f, sq = 0.0f;
    #pragma unroll
    for (int k = 0; k < TOUT / 256; ++k) {
        int t = threadIdx.x + k * 256;
        float val = resample_one(row, t, s, st);
        sum += val;
        sq += val * val;
    }

    waveReduce2(sum, sq);
    const int lane = threadIdx.x & 63;
    const int wid = threadIdx.x >> 6;
    if (lane == 0) wred[wid] = make_float2(sum, sq);
    __syncthreads();
    if (threadIdx.x == 0) {
        float S = 0.0f, Q = 0.0f;
        #pragma unroll
        for (int i = 0; i < 4; ++i) { S += wred[i].x; Q += wred[i].y; }
        partials[blk] = make_float2(S, Q);
    }
}

// -------- kernel 2: reduce batch partials -> per-feature affine (a, c) ------
__global__ __launch_bounds__(64) void k_stats(
    const float2* __restrict__ partials,
    const float* __restrict__ gamma,
    const float* __restrict__ beta,
    float2* __restrict__ stats)
{
    const int f = blockIdx.x;
    const int b = threadIdx.x;          // 64 threads = NB
    float2 p = partials[(size_t)b * NF + f];
    float S = p.x, Q = p.y;
    waveReduce2(S, Q);
    if (threadIdx.x == 0) {
        const float invN = 1.0f / (float)(NB * TOUT);
        float mean = S * invN;
        float var = Q * invN - mean * mean;
        float inv = 1.0f / sqrtf(var + BN_EPS);
        float a = gamma[f] * inv;
        float c = beta[f] - mean * a;
        stats[f] = make_float2(a, c);
    }
}

// -------- kernel 3: recompute resample, apply BN affine, write out ----------
__global__ __launch_bounds__(256) void k_apply(
    const float* __restrict__ data,
    const float* __restrict__ translate,
    const float* __restrict__ scale,
    const float2* __restrict__ stats,
    float* __restrict__ out)
{
    const int blk = blockIdx.x;
    const int f = blk & (NF - 1);
    const int b = blk >> 8;
    const size_t rowbase = ((size_t)b * NF + f) * (size_t)TIN;
    const float* row_g = data + rowbase;
    float* out_row = out + rowbase;     // TIN == TOUT

    __shared__ float row[TIN];
    {
        const float4* src4 = (const float4*)row_g;
        float4* dst4 = (float4*)row;
        #pragma unroll
        for (int i = 0; i < TIN / 4 / 256; ++i)
            dst4[threadIdx.x + i * 256] = src4[threadIdx.x + i * 256];
    }
    __syncthreads();

    const float s = expf(scale[f] / 5.0f);
    const float st = s * translate[f];
    const float2 ac = stats[f];

    #pragma unroll
    for (int k = 0; k < TOUT / 256; ++k) {
        int t = threadIdx.x + k * 256;
        float val = resample_one(row, t, s, st);
        out_row[t] = val * ac.x + ac.y;
    }
}

extern "C" void kernel_launch(void* const* d_in, const int* in_sizes, int n_in,
                              void* d_out, int out_size, void* d_ws, size_t ws_size,
                              hipStream_t stream) {
    const float* data      = (const float*)d_in[0];
    const float* translate = (const float*)d_in[1];
    const float* scale     = (const float*)d_in[2];
    const float* gamma     = (const float*)d_in[3];
    const float* beta      = (const float*)d_in[4];
    float* out = (float*)d_out;

    float2* partials = (float2*)d_ws;            // NB*NF float2 = 128 KB
    float2* stats    = partials + NB * NF;       // NF float2   = 2 KB

    k_resample_stats<<<NB * NF, 256, 0, stream>>>(data, translate, scale, partials);
    k_stats<<<NF, 64, 0, stream>>>(partials, gamma, beta, stats);
    k_apply<<<NB * NF, 256, 0, stream>>>(data, translate, scale, stats, out);
}

// Round 3
// 132.231 us; speedup vs baseline: 1.1625x; 1.1625x over previous
//
#include <hip/hip_runtime.h>

#define NB 64
#define NF 256
#define TIN 4096
#define TOUT 4096
#define BN_EPS 1e-5f

typedef float f32x4 __attribute__((ext_vector_type(4)));

// -------- helpers --------
__device__ __forceinline__ void waveReduce2(float& s, float& q) {
    #pragma unroll
    for (int off = 32; off > 0; off >>= 1) {
        s += __shfl_down(s, off, 64);
        q += __shfl_down(q, off, 64);
    }
}

// 4 consecutive output positions, exact reference op order in fp32
__device__ __forceinline__ f32x4 resample4(const float* __restrict__ row,
                                           int t0, float s, float st) {
    f32x4 r;
    #pragma unroll
    for (int j = 0; j < 4; ++j) {
        int t = t0 + j;
        float x = (2.0f * (float)t + 1.0f) * (1.0f / (float)TOUT) - 1.0f;
        float coord = s * x + st;
        float ix = ((coord + 1.0f) * (float)TIN - 1.0f) * 0.5f;
        float i0f = floorf(ix);
        float w = ix - i0f;
        int i0 = (int)i0f;
        int i1 = i0 + 1;
        float v0 = (i0 >= 0 && i0 < TIN) ? row[i0] : 0.0f;
        float v1 = (i1 >= 0 && i1 < TIN) ? row[i1] : 0.0f;
        r[j] = v0 * (1.0f - w) + v1 * w;
    }
    return r;
}

// -------- kernel 1: per-(b,f) row resample + partial sum/sumsq --------
__global__ __launch_bounds__(256) void k_resample_stats(
    const float* __restrict__ data,
    const float* __restrict__ translate,
    const float* __restrict__ scale,
    float2* __restrict__ partials)
{
    const int blk = blockIdx.x;
    const int f = blk & (NF - 1);
    const int b = blk >> 8;           // NF == 256
    const float* row_g = data + ((size_t)b * NF + f) * (size_t)TIN;

    __shared__ float row[TIN];
    __shared__ float2 wred[4];

    // stage row into LDS, coalesced 16B (regular loads: want L3 residency)
    {
        const f32x4* src4 = (const f32x4*)row_g;
        f32x4* dst4 = (f32x4*)row;
        #pragma unroll
        for (int i = 0; i < TIN / 4 / 256; ++i)
            dst4[threadIdx.x + i * 256] = src4[threadIdx.x + i * 256];
    }
    __syncthreads();

    const float s = expf(scale[f] / 5.0f);
    const float st = s * translate[f];

    float sum = 0.0f, sq = 0.0f;
    #pragma unroll
    for (int k = 0; k < 4; ++k) {
        int t0 = (threadIdx.x + k * 256) * 4;
        f32x4 v = resample4(row, t0, s, st);
        sum += v.x + v.y + v.z + v.w;
        sq += v.x * v.x + v.y * v.y + v.z * v.z + v.w * v.w;
    }

    waveReduce2(sum, sq);
    const int lane = threadIdx.x & 63;
    const int wid = threadIdx.x >> 6;
    if (lane == 0) wred[wid] = make_float2(sum, sq);
    __syncthreads();
    if (threadIdx.x == 0) {
        float S = 0.0f, Q = 0.0f;
        #pragma unroll
        for (int i = 0; i < 4; ++i) { S += wred[i].x; Q += wred[i].y; }
        partials[blk] = make_float2(S, Q);
    }
}

// -------- kernel 2: stats-fused apply: recompute resample, BN affine --------
__global__ __launch_bounds__(256) void k_apply(
    const float* __restrict__ data,
    const float* __restrict__ translate,
    const float* __restrict__ scale,
    const float2* __restrict__ partials,
    const float* __restrict__ gamma,
    const float* __restrict__ beta,
    float* __restrict__ out)
{
    const int blk = blockIdx.x;
    const int f = blk & (NF - 1);
    const int b = blk >> 8;
    const size_t rowbase = ((size_t)b * NF + f) * (size_t)TIN;
    const float* row_g = data + rowbase;
    float* out_row = out + rowbase;     // TIN == TOUT

    __shared__ float row[TIN];
    __shared__ float2 s_ac;

    // stage row into LDS — nontemporal loads (last touch of data)
    {
        const f32x4* src4 = (const f32x4*)row_g;
        f32x4* dst4 = (f32x4*)row;
        #pragma unroll
        for (int i = 0; i < TIN / 4 / 256; ++i)
            dst4[threadIdx.x + i * 256] =
                __builtin_nontemporal_load(&src4[threadIdx.x + i * 256]);
    }

    // wave 0: reduce the 64 batch partials for this feature -> (a, c)
    if (threadIdx.x < 64) {
        float2 p = partials[(size_t)threadIdx.x * NF + f];
        float S = p.x, Q = p.y;
        waveReduce2(S, Q);
        if (threadIdx.x == 0) {
            const float invN = 1.0f / (float)(NB * TOUT);
            float mean = S * invN;
            float var = Q * invN - mean * mean;
            float inv = 1.0f / sqrtf(var + BN_EPS);
            float a = gamma[f] * inv;
            s_ac = make_float2(a, beta[f] - mean * a);
        }
    }
    __syncthreads();

    const float s = expf(scale[f] / 5.0f);
    const float st = s * translate[f];
    const float a = s_ac.x;
    const float c = s_ac.y;

    #pragma unroll
    for (int k = 0; k < 4; ++k) {
        int t0 = (threadIdx.x + k * 256) * 4;
        f32x4 v = resample4(row, t0, s, st);
        v.x = v.x * a + c;
        v.y = v.y * a + c;
        v.z = v.z * a + c;
        v.w = v.w * a + c;
        __builtin_nontemporal_store(v, (f32x4*)(out_row + t0));
    }
}

extern "C" void kernel_launch(void* const* d_in, const int* in_sizes, int n_in,
                              void* d_out, int out_size, void* d_ws, size_t ws_size,
                              hipStream_t stream) {
    const float* data      = (const float*)d_in[0];
    const float* translate = (const float*)d_in[1];
    const float* scale     = (const float*)d_in[2];
    const float* gamma     = (const float*)d_in[3];
    const float* beta      = (const float*)d_in[4];
    float* out = (float*)d_out;

    float2* partials = (float2*)d_ws;            // NB*NF float2 = 128 KB

    k_resample_stats<<<NB * NF, 256, 0, stream>>>(data, translate, scale, partials);
    k_apply<<<NB * NF, 256, 0, stream>>>(data, translate, scale, partials,
                                         gamma, beta, out);
}